// Round 3
// baseline (135.373 us; speedup 1.0000x reference)
//
#include <hip/hip_runtime.h>

// HyperbolicAggregation: out = proj(expmap0(A @ x, c=1), c=1)
// A sparse (rows sorted), x [50000,128] f32.
// Kernel 1: O(E) coalesced row_ptr build (boundary scatter) -> d_ws.
// Kernel 2: one wave per node; float4 gathers, 2 edge-rows per load instr
//           (lanes 0-31 -> even edges, lanes 32-63 -> odd edges),
//           unroll ladder 16 / 4 / 2 edges per wave-iter for deep MLP.

#define MIN_NORM 1e-15f
#define PROJ_EPS 4e-3f

__global__ __launch_bounds__(256) void build_rowptr_kernel(
    const int* __restrict__ rows, int* __restrict__ row_ptr,
    int n_nodes, int n_edges)
{
    int e = blockIdx.x * blockDim.x + threadIdx.x;
    if (e >= n_edges) return;
    int r = rows[e];
    int prev = (e == 0) ? -1 : rows[e - 1];
    // row_ptr[node] = lower_bound(rows, node): fill boundary run.
    for (int node = prev + 1; node <= r; ++node) row_ptr[node] = e;
    if (e == n_edges - 1) {
        for (int node = r + 1; node <= n_nodes; ++node) row_ptr[node] = n_edges;
    }
}

__global__ __launch_bounds__(256) void hyp_agg_kernel(
    const float* __restrict__ x,
    const float* __restrict__ vals,
    const int* __restrict__ cols,
    const int* __restrict__ row_ptr,
    float* __restrict__ out,
    int n_nodes)
{
    const int node = (int)((blockIdx.x * blockDim.x + threadIdx.x) >> 6);
    const int lane = threadIdx.x & 63;
    if (node >= n_nodes) return;
    const int half = lane >> 5;    // 0: even edges, 1: odd edges
    const int l32  = lane & 31;    // float4 slot within the 128-f row

    const int start = row_ptr[node];
    const int end   = row_ptr[node + 1];
    const float4* __restrict__ x4 = reinterpret_cast<const float4*>(x);

    float ax = 0.f, ay = 0.f, az = 0.f, aw = 0.f;

    int e = start + half;
    // Big: 8 gathers per half in flight (16 edges per wave-iter).
    for (; e + 14 < end; e += 16) {
        float v[8]; int c[8];
        #pragma unroll
        for (int i = 0; i < 8; ++i) { v[i] = vals[e + 2 * i]; c[i] = cols[e + 2 * i]; }
        float4 xr[8];
        #pragma unroll
        for (int i = 0; i < 8; ++i) xr[i] = x4[(size_t)c[i] * 32 + l32];
        #pragma unroll
        for (int i = 0; i < 8; ++i) {
            ax = fmaf(v[i], xr[i].x, ax); ay = fmaf(v[i], xr[i].y, ay);
            az = fmaf(v[i], xr[i].z, az); aw = fmaf(v[i], xr[i].w, aw);
        }
    }
    // Mid: 2 gathers per half in flight (4 edges per wave-iter).
    for (; e + 2 < end; e += 4) {
        float v0 = vals[e], v1 = vals[e + 2];
        int   c0 = cols[e], c1 = cols[e + 2];
        float4 r0 = x4[(size_t)c0 * 32 + l32];
        float4 r1 = x4[(size_t)c1 * 32 + l32];
        ax = fmaf(v0, r0.x, ax); ay = fmaf(v0, r0.y, ay);
        az = fmaf(v0, r0.z, az); aw = fmaf(v0, r0.w, aw);
        ax = fmaf(v1, r1.x, ax); ay = fmaf(v1, r1.y, ay);
        az = fmaf(v1, r1.z, az); aw = fmaf(v1, r1.w, aw);
    }
    // Tail: one edge per half.
    for (; e < end; e += 2) {
        float v = vals[e];
        int   c = cols[e];
        float4 r0 = x4[(size_t)c * 32 + l32];
        ax = fmaf(v, r0.x, ax); ay = fmaf(v, r0.y, ay);
        az = fmaf(v, r0.z, az); aw = fmaf(v, r0.w, aw);
    }

    // Combine even/odd halves (lane i and i+32 hold the same feature slots).
    ax += __shfl_xor(ax, 32, 64);
    ay += __shfl_xor(ay, 32, 64);
    az += __shfl_xor(az, 32, 64);
    aw += __shfl_xor(aw, 32, 64);

    // Norm^2 across the 32-lane group.
    float nrm2 = fmaf(ax, ax, fmaf(ay, ay, fmaf(az, az, aw * aw)));
    #pragma unroll
    for (int off = 16; off > 0; off >>= 1) nrm2 += __shfl_xor(nrm2, off, 64);

    // expmap0 (sqrt_c=1): y = tanh(||u||)/||u|| * u;  proj uses ||y||==tanh(||u||).
    float u_norm = fmaxf(sqrtf(nrm2), MIN_NORM);
    float t = tanhf(u_norm);
    float scale = t / u_norm;
    const float maxnorm = 1.0f - PROJ_EPS;
    if (t > maxnorm) scale *= maxnorm / t;

    if (half == 0) {
        float4 y = make_float4(scale * ax, scale * ay, scale * az, scale * aw);
        reinterpret_cast<float4*>(out + (size_t)node * 128)[l32] = y;
    }
}

extern "C" void kernel_launch(void* const* d_in, const int* in_sizes, int n_in,
                              void* d_out, int out_size, void* d_ws, size_t ws_size,
                              hipStream_t stream) {
    const float* x    = (const float*)d_in[0];
    const float* vals = (const float*)d_in[1];
    const int*   rows = (const int*)d_in[2];
    const int*   cols = (const int*)d_in[3];
    float* out = (float*)d_out;

    const int d_feat  = 128;
    const int n_nodes = in_sizes[0] / d_feat;
    const int n_edges = in_sizes[1];

    int* row_ptr = (int*)d_ws;  // (n_nodes+1) ints; ws is ample
    {
        const int b1 = 256;
        const int g1 = (n_edges + b1 - 1) / b1;
        build_rowptr_kernel<<<g1, b1, 0, stream>>>(rows, row_ptr, n_nodes, n_edges);
    }

    const int block = 256;                 // 4 waves/block, 1 node per wave
    const int waves_per_block = block / 64;
    const int grid = (n_nodes + waves_per_block - 1) / waves_per_block;
    hyp_agg_kernel<<<grid, block, 0, stream>>>(x, vals, cols, row_ptr, out, n_nodes);
}

// Round 5
// 128.864 us; speedup vs baseline: 1.0505x; 1.0505x over previous
//
#include <hip/hip_runtime.h>
#include <hip/hip_fp16.h>

// HyperbolicAggregation: out = proj(expmap0(A @ x, c=1), c=1)
// A sparse (rows sorted), x [50000,128] f32.
// Kernel 0: convert x f32 -> f16 into d_ws (halves gather traffic; L2-friendlier).
// Kernel 1: O(E) coalesced row_ptr build -> d_ws.
// Kernel 2: one wave per node; lanes 0-31 handle even edges, 32-63 odd edges;
//           8-byte f16x4 gathers per lane, round-2 unroll depth
//           (4 gathers/half in flight), nontemporal edge loads / out stores.

#define MIN_NORM 1e-15f
#define PROJ_EPS 4e-3f

#define LDNT(p) __builtin_nontemporal_load(p)

typedef float floatx4 __attribute__((ext_vector_type(4)));

__device__ inline float h2f(unsigned short u) {
    __half h;
    __builtin_memcpy(&h, &u, sizeof(h));
    return __half2float(h);
}

__global__ __launch_bounds__(256) void cvt_f32_to_f16(
    const float4* __restrict__ x4, uint2* __restrict__ xh, int n4)
{
    int i = blockIdx.x * blockDim.x + threadIdx.x;
    if (i >= n4) return;
    float4 a = x4[i];
    __half2 lo = __floats2half2_rn(a.x, a.y);
    __half2 hi = __floats2half2_rn(a.z, a.w);
    uint2 o;
    o.x = *reinterpret_cast<unsigned int*>(&lo);
    o.y = *reinterpret_cast<unsigned int*>(&hi);
    xh[i] = o;
}

__global__ __launch_bounds__(256) void build_rowptr_kernel(
    const int* __restrict__ rows, int* __restrict__ row_ptr,
    int n_nodes, int n_edges)
{
    int e = blockIdx.x * blockDim.x + threadIdx.x;
    if (e >= n_edges) return;
    int r = rows[e];
    int prev = (e == 0) ? -1 : rows[e - 1];
    for (int node = prev + 1; node <= r; ++node) row_ptr[node] = e;
    if (e == n_edges - 1) {
        for (int node = r + 1; node <= n_nodes; ++node) row_ptr[node] = n_edges;
    }
}

// MODE 0: f16 x (from ws) + row_ptr.  MODE 1: f32 x + row_ptr.  MODE 2: f32 x + bsearch.
template <int MODE>
__global__ __launch_bounds__(256) void hyp_agg_kernel(
    const float* __restrict__ xf,
    const ushort4* __restrict__ xh,
    const float* __restrict__ vals,
    const int* __restrict__ rows,
    const int* __restrict__ cols,
    const int* __restrict__ row_ptr,
    float* __restrict__ out,
    int n_nodes, int n_edges)
{
    const int node = (int)((blockIdx.x * blockDim.x + threadIdx.x) >> 6);
    const int lane = threadIdx.x & 63;
    if (node >= n_nodes) return;
    const int half = lane >> 5;    // 0: even edges, 1: odd edges
    const int l32  = lane & 31;    // f16x4 / f32x4 slot within the 128-wide row

    int start, end;
    if constexpr (MODE == 2) {
        int lo = 0, hi = n_edges;
        while (lo < hi) { int mid = (lo + hi) >> 1; if (rows[mid] < node) lo = mid + 1; else hi = mid; }
        start = lo; hi = n_edges;
        while (lo < hi) { int mid = (lo + hi) >> 1; if (rows[mid] <= node) lo = mid + 1; else hi = mid; }
        end = lo;
    } else {
        start = row_ptr[node];
        end   = row_ptr[node + 1];
    }

    const float4* __restrict__ x4 = reinterpret_cast<const float4*>(xf);

    float ax = 0.f, ay = 0.f, az = 0.f, aw = 0.f;

    int e = start + half;
    // 4 gathers per half-wave in flight (8 edges per wave-iter).
    for (; e + 6 < end; e += 8) {
        float v0 = LDNT(vals + e),     v1 = LDNT(vals + e + 2);
        float v2 = LDNT(vals + e + 4), v3 = LDNT(vals + e + 6);
        int   c0 = LDNT(cols + e),     c1 = LDNT(cols + e + 2);
        int   c2 = LDNT(cols + e + 4), c3 = LDNT(cols + e + 6);
        if constexpr (MODE == 0) {
            ushort4 r0 = xh[(size_t)c0 * 32 + l32];
            ushort4 r1 = xh[(size_t)c1 * 32 + l32];
            ushort4 r2 = xh[(size_t)c2 * 32 + l32];
            ushort4 r3 = xh[(size_t)c3 * 32 + l32];
            ax = fmaf(v0, h2f(r0.x), ax); ay = fmaf(v0, h2f(r0.y), ay);
            az = fmaf(v0, h2f(r0.z), az); aw = fmaf(v0, h2f(r0.w), aw);
            ax = fmaf(v1, h2f(r1.x), ax); ay = fmaf(v1, h2f(r1.y), ay);
            az = fmaf(v1, h2f(r1.z), az); aw = fmaf(v1, h2f(r1.w), aw);
            ax = fmaf(v2, h2f(r2.x), ax); ay = fmaf(v2, h2f(r2.y), ay);
            az = fmaf(v2, h2f(r2.z), az); aw = fmaf(v2, h2f(r2.w), aw);
            ax = fmaf(v3, h2f(r3.x), ax); ay = fmaf(v3, h2f(r3.y), ay);
            az = fmaf(v3, h2f(r3.z), az); aw = fmaf(v3, h2f(r3.w), aw);
        } else {
            float4 r0 = x4[(size_t)c0 * 32 + l32];
            float4 r1 = x4[(size_t)c1 * 32 + l32];
            float4 r2 = x4[(size_t)c2 * 32 + l32];
            float4 r3 = x4[(size_t)c3 * 32 + l32];
            ax = fmaf(v0, r0.x, ax); ay = fmaf(v0, r0.y, ay);
            az = fmaf(v0, r0.z, az); aw = fmaf(v0, r0.w, aw);
            ax = fmaf(v1, r1.x, ax); ay = fmaf(v1, r1.y, ay);
            az = fmaf(v1, r1.z, az); aw = fmaf(v1, r1.w, aw);
            ax = fmaf(v2, r2.x, ax); ay = fmaf(v2, r2.y, ay);
            az = fmaf(v2, r2.z, az); aw = fmaf(v2, r2.w, aw);
            ax = fmaf(v3, r3.x, ax); ay = fmaf(v3, r3.y, ay);
            az = fmaf(v3, r3.z, az); aw = fmaf(v3, r3.w, aw);
        }
    }
    // Tail: one edge per half.
    for (; e < end; e += 2) {
        float v = LDNT(vals + e);
        int   c = LDNT(cols + e);
        if constexpr (MODE == 0) {
            ushort4 r0 = xh[(size_t)c * 32 + l32];
            ax = fmaf(v, h2f(r0.x), ax); ay = fmaf(v, h2f(r0.y), ay);
            az = fmaf(v, h2f(r0.z), az); aw = fmaf(v, h2f(r0.w), aw);
        } else {
            float4 r0 = x4[(size_t)c * 32 + l32];
            ax = fmaf(v, r0.x, ax); ay = fmaf(v, r0.y, ay);
            az = fmaf(v, r0.z, az); aw = fmaf(v, r0.w, aw);
        }
    }

    // Combine even/odd halves (lane i and i+32 hold the same feature slots).
    ax += __shfl_xor(ax, 32, 64);
    ay += __shfl_xor(ay, 32, 64);
    az += __shfl_xor(az, 32, 64);
    aw += __shfl_xor(aw, 32, 64);

    // Norm^2 across the 32-lane group.
    float nrm2 = fmaf(ax, ax, fmaf(ay, ay, fmaf(az, az, aw * aw)));
    #pragma unroll
    for (int off = 16; off > 0; off >>= 1) nrm2 += __shfl_xor(nrm2, off, 64);

    // expmap0 (sqrt_c=1): y = tanh(||u||)/||u|| * u;  proj uses ||y||==tanh(||u||).
    float u_norm = fmaxf(sqrtf(nrm2), MIN_NORM);
    float t = tanhf(u_norm);
    float scale = t / u_norm;
    const float maxnorm = 1.0f - PROJ_EPS;
    if (t > maxnorm) scale *= maxnorm / t;

    if (half == 0) {
        floatx4 y;
        y.x = scale * ax; y.y = scale * ay; y.z = scale * az; y.w = scale * aw;
        __builtin_nontemporal_store(y, reinterpret_cast<floatx4*>(out + (size_t)node * 128) + l32);
    }
}

extern "C" void kernel_launch(void* const* d_in, const int* in_sizes, int n_in,
                              void* d_out, int out_size, void* d_ws, size_t ws_size,
                              hipStream_t stream) {
    const float* x    = (const float*)d_in[0];
    const float* vals = (const float*)d_in[1];
    const int*   rows = (const int*)d_in[2];
    const int*   cols = (const int*)d_in[3];
    float* out = (float*)d_out;

    const int d_feat  = 128;
    const int n_nodes = in_sizes[0] / d_feat;
    const int n_edges = in_sizes[1];

    char* ws = (char*)d_ws;
    const size_t rp_bytes = (((size_t)(n_nodes + 1) * sizeof(int)) + 255) & ~(size_t)255;
    const size_t xh_bytes = (size_t)n_nodes * d_feat * sizeof(unsigned short);

    int*     row_ptr = nullptr;
    ushort4* xh      = nullptr;

    if (ws && ws_size >= rp_bytes) {
        row_ptr = (int*)ws;
        const int b = 256, g = (n_edges + b - 1) / b;
        build_rowptr_kernel<<<g, b, 0, stream>>>(rows, row_ptr, n_nodes, n_edges);
    }
    if (row_ptr && ws_size >= rp_bytes + xh_bytes) {
        xh = (ushort4*)(ws + rp_bytes);
        const int n4 = n_nodes * (d_feat / 4);
        const int b = 256, g = (n4 + b - 1) / b;
        cvt_f32_to_f16<<<g, b, 0, stream>>>(reinterpret_cast<const float4*>(x),
                                            reinterpret_cast<uint2*>(xh), n4);
    }

    const int block = 256;                 // 4 waves/block, 1 node per wave
    const int waves_per_block = block / 64;
    const int grid = (n_nodes + waves_per_block - 1) / waves_per_block;

    if (xh) {
        hyp_agg_kernel<0><<<grid, block, 0, stream>>>(x, xh, vals, rows, cols, row_ptr,
                                                      out, n_nodes, n_edges);
    } else if (row_ptr) {
        hyp_agg_kernel<1><<<grid, block, 0, stream>>>(x, nullptr, vals, rows, cols, row_ptr,
                                                      out, n_nodes, n_edges);
    } else {
        hyp_agg_kernel<2><<<grid, block, 0, stream>>>(x, nullptr, vals, rows, cols, nullptr,
                                                      out, n_nodes, n_edges);
    }
}

// Round 7
// 117.563 us; speedup vs baseline: 1.1515x; 1.0961x over previous
//
#include <hip/hip_runtime.h>
#include <hip/hip_fp16.h>

// HyperbolicAggregation: out = proj(expmap0(A @ x, c=1), c=1)
// A sparse (rows sorted), x [50000,128] f32.
// Kernel 0: convert x f32 -> f16 into d_ws (halves gather traffic).
// Kernel 1: O(E) coalesced row_ptr build -> d_ws.
// Kernel 2: one wave per node. Per <=64-edge chunk the wave stages cols/vals
//           into its own LDS slice (one coalesced load), then reads per-edge
//           scalars from LDS (2-address broadcast, conflict-free, in-order
//           within a wave -> no barrier). Lanes 0-31 do even edges, 32-63 odd;
//           8-B f16x4 gathers, 4 in flight per half; NT loads/stores.

#define MIN_NORM 1e-15f
#define PROJ_EPS 4e-3f

#define LDNT(p) __builtin_nontemporal_load(p)

typedef float floatx4 __attribute__((ext_vector_type(4)));

__device__ inline float h2f(unsigned short u) {
    __half h;
    __builtin_memcpy(&h, &u, sizeof(h));
    return __half2float(h);
}

__global__ __launch_bounds__(256) void cvt_f32_to_f16(
    const float4* __restrict__ x4, uint2* __restrict__ xh, int n4)
{
    int i = blockIdx.x * blockDim.x + threadIdx.x;
    if (i >= n4) return;
    float4 a = x4[i];
    __half2 lo = __floats2half2_rn(a.x, a.y);
    __half2 hi = __floats2half2_rn(a.z, a.w);
    uint2 o;
    o.x = *reinterpret_cast<unsigned int*>(&lo);
    o.y = *reinterpret_cast<unsigned int*>(&hi);
    xh[i] = o;
}

__global__ __launch_bounds__(256) void build_rowptr_kernel(
    const int* __restrict__ rows, int* __restrict__ row_ptr,
    int n_nodes, int n_edges)
{
    int e = blockIdx.x * blockDim.x + threadIdx.x;
    if (e >= n_edges) return;
    int r = rows[e];
    int prev = (e == 0) ? -1 : rows[e - 1];
    for (int node = prev + 1; node <= r; ++node) row_ptr[node] = e;
    if (e == n_edges - 1) {
        for (int node = r + 1; node <= n_nodes; ++node) row_ptr[node] = n_edges;
    }
}

// MODE 0: f16 x (ws) + row_ptr.  MODE 2: f32 x + inline binary search (fallback).
template <int MODE>
__global__ __launch_bounds__(256) void hyp_agg_kernel(
    const float* __restrict__ xf,
    const ushort4* __restrict__ xh,
    const float* __restrict__ vals,
    const int* __restrict__ rows,
    const int* __restrict__ cols,
    const int* __restrict__ row_ptr,
    float* __restrict__ out,
    int n_nodes, int n_edges)
{
    __shared__ int   s_c[4][64];
    __shared__ float s_v[4][64];

    const int tid  = threadIdx.x;
    const int node = (int)((blockIdx.x * blockDim.x + tid) >> 6);
    if (node >= n_nodes) return;
    const int wv   = tid >> 6;     // wave within block (own LDS slice)
    const int lane = tid & 63;
    const int half = lane >> 5;    // 0: even edges of pair, 1: odd
    const int l32  = lane & 31;    // 8B (f16x4) / 16B (f32x4) slot in the row

    int start, end;
    if constexpr (MODE == 2) {
        int lo = 0, hi = n_edges;
        while (lo < hi) { int mid = (lo + hi) >> 1; if (rows[mid] < node) lo = mid + 1; else hi = mid; }
        start = lo; hi = n_edges;
        while (lo < hi) { int mid = (lo + hi) >> 1; if (rows[mid] <= node) lo = mid + 1; else hi = mid; }
        end = lo;
    } else {
        start = row_ptr[node];
        end   = row_ptr[node + 1];
    }

    const float4* __restrict__ x4 = reinterpret_cast<const float4*>(xf);

    float ax = 0.f, ay = 0.f, az = 0.f, aw = 0.f;

    for (int base = start; base < end; base += 64) {
        const int navail = min(64, end - base);
        const int idx = base + lane;
        if (lane < navail) {
            s_c[wv][lane] = LDNT(cols + idx);
            s_v[wv][lane] = LDNT(vals + idx);
        }
        // Same-wave LDS write->read is in-order in HW; no barrier needed
        // (each wave touches only its own slice).

        int j = 0;
        // 4 pair-steps per iter: 4 gathers in flight per half, 8 edges.
        for (; j + 7 < navail; j += 8) {
            int   c0 = s_c[wv][j + 0 + half]; float v0 = s_v[wv][j + 0 + half];
            int   c1 = s_c[wv][j + 2 + half]; float v1 = s_v[wv][j + 2 + half];
            int   c2 = s_c[wv][j + 4 + half]; float v2 = s_v[wv][j + 4 + half];
            int   c3 = s_c[wv][j + 6 + half]; float v3 = s_v[wv][j + 6 + half];
            if constexpr (MODE == 0) {
                ushort4 r0 = xh[(size_t)c0 * 32 + l32];
                ushort4 r1 = xh[(size_t)c1 * 32 + l32];
                ushort4 r2 = xh[(size_t)c2 * 32 + l32];
                ushort4 r3 = xh[(size_t)c3 * 32 + l32];
                ax = fmaf(v0, h2f(r0.x), ax); ay = fmaf(v0, h2f(r0.y), ay);
                az = fmaf(v0, h2f(r0.z), az); aw = fmaf(v0, h2f(r0.w), aw);
                ax = fmaf(v1, h2f(r1.x), ax); ay = fmaf(v1, h2f(r1.y), ay);
                az = fmaf(v1, h2f(r1.z), az); aw = fmaf(v1, h2f(r1.w), aw);
                ax = fmaf(v2, h2f(r2.x), ax); ay = fmaf(v2, h2f(r2.y), ay);
                az = fmaf(v2, h2f(r2.z), az); aw = fmaf(v2, h2f(r2.w), aw);
                ax = fmaf(v3, h2f(r3.x), ax); ay = fmaf(v3, h2f(r3.y), ay);
                az = fmaf(v3, h2f(r3.z), az); aw = fmaf(v3, h2f(r3.w), aw);
            } else {
                float4 r0 = x4[(size_t)c0 * 32 + l32];
                float4 r1 = x4[(size_t)c1 * 32 + l32];
                float4 r2 = x4[(size_t)c2 * 32 + l32];
                float4 r3 = x4[(size_t)c3 * 32 + l32];
                ax = fmaf(v0, r0.x, ax); ay = fmaf(v0, r0.y, ay);
                az = fmaf(v0, r0.z, az); aw = fmaf(v0, r0.w, aw);
                ax = fmaf(v1, r1.x, ax); ay = fmaf(v1, r1.y, ay);
                az = fmaf(v1, r1.z, az); aw = fmaf(v1, r1.w, aw);
                ax = fmaf(v2, r2.x, ax); ay = fmaf(v2, r2.y, ay);
                az = fmaf(v2, r2.z, az); aw = fmaf(v2, r2.w, aw);
                ax = fmaf(v3, r3.x, ax); ay = fmaf(v3, r3.y, ay);
                az = fmaf(v3, r3.z, az); aw = fmaf(v3, r3.w, aw);
            }
        }
        // Pair tail.
        for (; j + 1 < navail; j += 2) {
            int   c0 = s_c[wv][j + half];
            float v0 = s_v[wv][j + half];
            if constexpr (MODE == 0) {
                ushort4 r0 = xh[(size_t)c0 * 32 + l32];
                ax = fmaf(v0, h2f(r0.x), ax); ay = fmaf(v0, h2f(r0.y), ay);
                az = fmaf(v0, h2f(r0.z), az); aw = fmaf(v0, h2f(r0.w), aw);
            } else {
                float4 r0 = x4[(size_t)c0 * 32 + l32];
                ax = fmaf(v0, r0.x, ax); ay = fmaf(v0, r0.y, ay);
                az = fmaf(v0, r0.z, az); aw = fmaf(v0, r0.w, aw);
            }
        }
        // Odd last edge: only lower half contributes (v=0 on upper half).
        if (j < navail) {
            int   c0 = s_c[wv][j];
            float v0 = half ? 0.f : s_v[wv][j];
            if constexpr (MODE == 0) {
                ushort4 r0 = xh[(size_t)c0 * 32 + l32];
                ax = fmaf(v0, h2f(r0.x), ax); ay = fmaf(v0, h2f(r0.y), ay);
                az = fmaf(v0, h2f(r0.z), az); aw = fmaf(v0, h2f(r0.w), aw);
            } else {
                float4 r0 = x4[(size_t)c0 * 32 + l32];
                ax = fmaf(v0, r0.x, ax); ay = fmaf(v0, r0.y, ay);
                az = fmaf(v0, r0.z, az); aw = fmaf(v0, r0.w, aw);
            }
        }
    }

    // Combine even/odd halves (lane i and i+32 hold the same feature slots).
    ax += __shfl_xor(ax, 32, 64);
    ay += __shfl_xor(ay, 32, 64);
    az += __shfl_xor(az, 32, 64);
    aw += __shfl_xor(aw, 32, 64);

    // Norm^2 across the 32-lane group.
    float nrm2 = fmaf(ax, ax, fmaf(ay, ay, fmaf(az, az, aw * aw)));
    #pragma unroll
    for (int off = 16; off > 0; off >>= 1) nrm2 += __shfl_xor(nrm2, off, 64);

    // expmap0 (sqrt_c=1): y = tanh(||u||)/||u|| * u;  proj uses ||y||==tanh(||u||).
    float u_norm = fmaxf(sqrtf(nrm2), MIN_NORM);
    float t = tanhf(u_norm);
    float scale = t / u_norm;
    const float maxnorm = 1.0f - PROJ_EPS;
    if (t > maxnorm) scale *= maxnorm / t;

    if (half == 0) {
        floatx4 y;
        y.x = scale * ax; y.y = scale * ay; y.z = scale * az; y.w = scale * aw;
        __builtin_nontemporal_store(y, reinterpret_cast<floatx4*>(out + (size_t)node * 128) + l32);
    }
}

extern "C" void kernel_launch(void* const* d_in, const int* in_sizes, int n_in,
                              void* d_out, int out_size, void* d_ws, size_t ws_size,
                              hipStream_t stream) {
    const float* x    = (const float*)d_in[0];
    const float* vals = (const float*)d_in[1];
    const int*   rows = (const int*)d_in[2];
    const int*   cols = (const int*)d_in[3];
    float* out = (float*)d_out;

    const int d_feat  = 128;
    const int n_nodes = in_sizes[0] / d_feat;
    const int n_edges = in_sizes[1];

    char* ws = (char*)d_ws;
    const size_t rp_bytes = (((size_t)(n_nodes + 1) * sizeof(int)) + 255) & ~(size_t)255;
    const size_t xh_bytes = (size_t)n_nodes * d_feat * sizeof(unsigned short);

    int*     row_ptr = nullptr;
    ushort4* xh      = nullptr;

    if (ws && ws_size >= rp_bytes + xh_bytes) {
        row_ptr = (int*)ws;
        xh      = (ushort4*)(ws + rp_bytes);
        {
            const int b = 256, g = (n_edges + b - 1) / b;
            build_rowptr_kernel<<<g, b, 0, stream>>>(rows, row_ptr, n_nodes, n_edges);
        }
        {
            const int n4 = n_nodes * (d_feat / 4);
            const int b = 256, g = (n4 + b - 1) / b;
            cvt_f32_to_f16<<<g, b, 0, stream>>>(reinterpret_cast<const float4*>(x),
                                                reinterpret_cast<uint2*>(xh), n4);
        }
    }

    const int block = 256;                 // 4 waves/block, 1 node per wave
    const int waves_per_block = block / 64;
    const int grid = (n_nodes + waves_per_block - 1) / waves_per_block;

    if (xh) {
        hyp_agg_kernel<0><<<grid, block, 0, stream>>>(x, xh, vals, rows, cols, row_ptr,
                                                      out, n_nodes, n_edges);
    } else {
        hyp_agg_kernel<2><<<grid, block, 0, stream>>>(x, nullptr, vals, rows, cols, nullptr,
                                                      out, n_nodes, n_edges);
    }
}